// Round 5
// baseline (200.727 us; speedup 1.0000x reference)
//
#include <hip/hip_runtime.h>
#include <hip/hip_bf16.h>
#include <math.h>

#define BSZ 2
#define NQ 4096
#define DIM 768
#define HEADS 6
#define POINTS 4
#define HD 128
#define HW_DIM 64
#define NV (HW_DIM*HW_DIM)
#define M_TOTAL (BSZ*NQ)   // 8192
#define KDIM 768
#define KSPLIT 4
#define KPART (KDIM/KSPLIT)  // 192

#define BM 64
#define BN 128
#define BKK 64
#define NBLK_M (M_TOTAL/BM)   // 128
#define NBLK_N (DIM/BN)       // 6
#define GEMM_GRID (NBLK_M*NBLK_N) // 768

typedef __attribute__((ext_vector_type(8))) short bf16x8;
typedef __attribute__((ext_vector_type(4))) float f32x4;
typedef unsigned int u32;
typedef unsigned short u16;

__device__ inline u16 f2bf(float f) {
    union { float f; u32 u; } v; v.f = f;
    u32 r = v.u + 0x7fffu + ((v.u >> 16) & 1u);
    return (u16)(r >> 16);
}

#define GLD16(g, l) __builtin_amdgcn_global_load_lds( \
    (const __attribute__((address_space(1))) u32*)(g), \
    (__attribute__((address_space(3))) u32*)(l), 16, 0, 0)

// ---------------- LayerNorm, wave-per-row, barrier-free --------------------
// block 256 = 4 waves = 4 rows; lane covers 12 elems (3x float4)
__global__ __launch_bounds__(256) void ln_bf_kernel(const float* __restrict__ x,
        const float* __restrict__ w, const float* __restrict__ b,
        u16* __restrict__ q) {
    int wave = threadIdx.x >> 6, lane = threadIdx.x & 63;
    int row = blockIdx.x * 4 + wave;
    int c = lane * 4;
    const float* xr = x + (size_t)row * DIM;
    float4 v0 = *(const float4*)(xr + c);
    float4 v1 = *(const float4*)(xr + c + 256);
    float4 v2 = *(const float4*)(xr + c + 512);
    float s  = v0.x+v0.y+v0.z+v0.w + v1.x+v1.y+v1.z+v1.w + v2.x+v2.y+v2.z+v2.w;
    float ss = v0.x*v0.x+v0.y*v0.y+v0.z*v0.z+v0.w*v0.w
             + v1.x*v1.x+v1.y*v1.y+v1.z*v1.z+v1.w*v1.w
             + v2.x*v2.x+v2.y*v2.y+v2.z*v2.z+v2.w*v2.w;
    #pragma unroll
    for (int st = 1; st < 64; st <<= 1) {
        s  += __shfl_xor(s,  st, 64);
        ss += __shfl_xor(ss, st, 64);
    }
    float mean = s * (1.0f / DIM);
    float var  = ss * (1.0f / DIM) - mean * mean;
    float rstd = rsqrtf(var + 1e-6f);
    u16* qr = q + (size_t)row * DIM;
    #pragma unroll
    for (int g = 0; g < 3; g++) {
        float4 v = (g == 0) ? v0 : (g == 1) ? v1 : v2;
        int cc = c + g * 256;
        const float4 ww = *(const float4*)(w + cc);
        const float4 bb = *(const float4*)(b + cc);
        ushort4 o;
        o.x = f2bf((v.x - mean) * rstd * ww.x + bb.x);
        o.y = f2bf((v.y - mean) * rstd * ww.y + bb.y);
        o.z = f2bf((v.z - mean) * rstd * ww.z + bb.z);
        o.w = f2bf((v.w - mean) * rstd * ww.w + bb.w);
        *(ushort4*)(qr + cc) = o;
    }
}

// ---------------- all weight transposes in one launch ----------------------
__global__ __launch_bounds__(256) void transpose_all(
        const float* __restrict__ vp_w,  u16* __restrict__ vp_wt,
        const float* __restrict__ out_w, u16* __restrict__ out_wt,
        const float* __restrict__ off_w, const float* __restrict__ aw_w,
        u16* __restrict__ oaw_wt) {
    int z = blockIdx.z;
    if (z == 2 && blockIdx.x >= 3) return;
    __shared__ float tile[32][33];
    int n0 = blockIdx.x * 32, k0 = blockIdx.y * 32;
    int tx = threadIdx.x & 31, ty = threadIdx.x >> 5;
    const float* src = (z == 0) ? vp_w : (z == 1) ? out_w : nullptr;
    u16* dst = (z == 0) ? vp_wt : (z == 1) ? out_wt : oaw_wt;
    #pragma unroll
    for (int r = 0; r < 4; r++) {
        int k = k0 + ty + r * 8, n = n0 + tx;
        float v = 0.0f;
        if (z < 2) {
            v = src[(size_t)k * DIM + n];
        } else {
            if (n < 48) v = off_w[(size_t)k * 48 + n];
            else if (n < 72) v = aw_w[(size_t)k * 24 + (n - 48)];
        }
        tile[ty + r * 8][tx] = v;
    }
    __syncthreads();
    #pragma unroll
    for (int r = 0; r < 4; r++) {
        int nn = ty + r * 8, kk = tx;
        int drow = n0 + nn;
        if (z == 2 && drow >= 80) continue;
        dst[(size_t)drow * KDIM + k0 + kk] = f2bf(tile[kk][nn]);
    }
}

// ---------------- big GEMM: 64x128 tile, BK=64, XCD-swizzled ---------------
// AFP32=0: A bf16 via global_load_lds ; AFP32=1: A fp32, cvt in VGPR, ds_write
template<int AFP32>
__global__ __launch_bounds__(256, 3) void gemm_bt(
        const void* __restrict__ Avoid, const u16* __restrict__ Bt,
        const float* __restrict__ bias, void* __restrict__ Cout,
        int storeBF16, const float* __restrict__ resid,
        const float* __restrict__ gamma) {
    __shared__ u16 As[BM * BKK];   // 8 KB
    __shared__ u16 Bs[BN * BKK];   // 16 KB
    int tid = threadIdx.x, w = tid >> 6, lane = tid & 63;
    int lm = lane & 15, quad = lane >> 4;
    int b = blockIdx.x;
    int xcd = b & 7, idx = b >> 3;        // idx: 0..95
    int mb = xcd * 16 + idx / NBLK_N;
    int nb = idx % NBLK_N;
    int m0 = mb * BM, n0 = nb * BN;
    int wr = w & 1, wc = w >> 1;

    int srow = lane >> 3;               // 0..7
    int scol = (lane & 7) ^ srow;       // XOR-swizzled source col-block
    const u16* Bb = Bt + (size_t)n0 * KDIM;
    const u16* Ab16 = (const u16*)Avoid + (size_t)m0 * KDIM;
    const float* Ab32 = (const float*)Avoid + (size_t)m0 * KDIM;
    // fp32-A staging pattern: thread t -> row t>>2, cols (t&3)*16 .. +15
    int arow = tid >> 2, acb0 = (tid & 3) * 2;   // two logical col-blocks of 8

    f32x4 acc[2][4];
    #pragma unroll
    for (int i = 0; i < 2; i++)
        #pragma unroll
        for (int j = 0; j < 4; j++) acc[i][j] = (f32x4){0.f, 0.f, 0.f, 0.f};

    const u16* aaddr[2][2];
    const u16* baddr[4][2];
    #pragma unroll
    for (int i = 0; i < 2; i++) {
        int row = wr * 32 + i * 16 + lm;
        #pragma unroll
        for (int kk = 0; kk < 2; kk++)
            aaddr[i][kk] = &As[row * BKK + (((quad + 4 * kk) ^ (row & 7)) << 3)];
    }
    #pragma unroll
    for (int j = 0; j < 4; j++) {
        int row = wc * 64 + j * 16 + lm;
        #pragma unroll
        for (int kk = 0; kk < 2; kk++)
            baddr[j][kk] = &Bs[row * BKK + (((quad + 4 * kk) ^ (row & 7)) << 3)];
    }

    for (int k0 = 0; k0 < KDIM; k0 += BKK) {
        if (AFP32) {
            const float* ag = Ab32 + (size_t)arow * KDIM + k0 + acb0 * 8;
            float4 f0 = *(const float4*)ag;
            float4 f1 = *(const float4*)(ag + 4);
            float4 f2 = *(const float4*)(ag + 8);
            float4 f3 = *(const float4*)(ag + 12);
            bf16x8 p0, p1;
            p0[0]=f2bf(f0.x); p0[1]=f2bf(f0.y); p0[2]=f2bf(f0.z); p0[3]=f2bf(f0.w);
            p0[4]=f2bf(f1.x); p0[5]=f2bf(f1.y); p0[6]=f2bf(f1.z); p0[7]=f2bf(f1.w);
            p1[0]=f2bf(f2.x); p1[1]=f2bf(f2.y); p1[2]=f2bf(f2.z); p1[3]=f2bf(f2.w);
            p1[4]=f2bf(f3.x); p1[5]=f2bf(f3.y); p1[6]=f2bf(f3.z); p1[7]=f2bf(f3.w);
            *(bf16x8*)&As[arow * BKK + (((acb0)     ^ (arow & 7)) << 3)] = p0;
            *(bf16x8*)&As[arow * BKK + (((acb0 + 1) ^ (arow & 7)) << 3)] = p1;
        } else {
            #pragma unroll
            for (int r = 0; r < 2; r++) {
                int row = r * 32 + w * 8 + srow;
                GLD16(Ab16 + (size_t)row * KDIM + k0 + scol * 8, &As[(r * 32 + w * 8) * BKK]);
            }
        }
        #pragma unroll
        for (int r = 0; r < 4; r++) {
            int row = r * 32 + w * 8 + srow;
            GLD16(Bb + (size_t)row * KDIM + k0 + scol * 8, &Bs[(r * 32 + w * 8) * BKK]);
        }
        __syncthreads();
        #pragma unroll
        for (int kk = 0; kk < 2; kk++) {
            bf16x8 af[2], bf[4];
            #pragma unroll
            for (int i = 0; i < 2; i++) af[i] = *(const bf16x8*)aaddr[i][kk];
            #pragma unroll
            for (int j = 0; j < 4; j++) bf[j] = *(const bf16x8*)baddr[j][kk];
            #pragma unroll
            for (int i = 0; i < 2; i++)
                #pragma unroll
                for (int j = 0; j < 4; j++)
                    acc[i][j] = __builtin_amdgcn_mfma_f32_16x16x32_bf16(af[i], bf[j], acc[i][j], 0, 0, 0);
        }
        __syncthreads();
    }

    #pragma unroll
    for (int j = 0; j < 4; j++) {
        int col = n0 + wc * 64 + j * 16 + lm;
        float bb = bias[col];
        #pragma unroll
        for (int i = 0; i < 2; i++) {
            #pragma unroll
            for (int r = 0; r < 4; r++) {
                int row = m0 + wr * 32 + i * 16 + quad * 4 + r;
                size_t idxo = (size_t)row * DIM + col;
                float v = acc[i][j][r] + bb;
                if (storeBF16) {
                    ((u16*)Cout)[idxo] = f2bf(v);
                } else {
                    ((float*)Cout)[idxo] = resid[idxo] + gamma[col] * v;
                }
            }
        }
    }
}

// ---------------- small GEMM, K-split: q[M][Kpart] * Wt[80][Kpart] ---------
__global__ __launch_bounds__(256, 2) void gemm_small(
        const u16* __restrict__ A, const u16* __restrict__ Bt,
        const float* __restrict__ b0, const float* __restrict__ b1,
        float* __restrict__ C, int M, int K) {
    __shared__ u16 As[64 * 32];
    __shared__ u16 Bs[80 * 32];
    int tid = threadIdx.x, wave = tid >> 6, lane = tid & 63;
    int lm = lane & 15, quad = lane >> 4;
    int m0 = blockIdx.x * 64;
    int part = blockIdx.y;
    int kbase = part * KPART;
    f32x4 acc[5];
    #pragma unroll
    for (int i = 0; i < 5; i++) acc[i] = (f32x4){0.f, 0.f, 0.f, 0.f};
    int lrow = lane >> 2, lcol = (lane & 3) * 8;

    for (int k0 = kbase; k0 < kbase + KPART; k0 += 32) {
        for (int c = wave; c < 9; c += 4) {
            if (c < 4) {
                GLD16(A + (size_t)(m0 + c * 16 + lrow) * K + k0 + lcol, &As[c * 16 * 32]);
            } else {
                GLD16(Bt + (size_t)((c - 4) * 16 + lrow) * K + k0 + lcol, &Bs[(c - 4) * 16 * 32]);
            }
        }
        __syncthreads();
        bf16x8 af = *(const bf16x8*)&As[(wave * 16 + lm) * 32 + quad * 8];
        #pragma unroll
        for (int bn = 0; bn < 5; bn++) {
            bf16x8 bv = *(const bf16x8*)&Bs[(bn * 16 + lm) * 32 + quad * 8];
            acc[bn] = __builtin_amdgcn_mfma_f32_16x16x32_bf16(af, bv, acc[bn], 0, 0, 0);
        }
        __syncthreads();
    }
    float* Cp = C + (size_t)part * M_TOTAL * 80;
    #pragma unroll
    for (int bn = 0; bn < 5; bn++) {
        int col = bn * 16 + lm;
        float bb = 0.0f;
        if (part == 0) bb = (col < 48) ? b0[col] : ((col < 72) ? b1[col - 48] : 0.0f);
        #pragma unroll
        for (int r = 0; r < 4; r++) {
            int row = m0 + wave * 16 + quad * 4 + r;
            Cp[(size_t)row * 80 + col] = acc[bn][r] + bb;
        }
    }
}

// ---------------- softmax(24) + bilinear sampling, predicated loads --------
__global__ __launch_bounds__(384) void sample_kernel(
        const float* __restrict__ oa, const float* __restrict__ refp,
        const u16* __restrict__ v, u16* __restrict__ out) {
    int row = blockIdx.x;
    int b = row >> 12;                 // NQ = 4096
    int tid = threadIdx.x;
    __shared__ float s_w[4][24];
    __shared__ int   s_o[4][24];
    __shared__ float s_e[24];
    if (tid < 24) {
        int h = tid >> 2, p = tid & 3;
        float ox = 0.f, oy = 0.f, lg = 0.f;
        #pragma unroll
        for (int part = 0; part < KSPLIT; part++) {
            const float* pp = oa + (size_t)part * M_TOTAL * 80 + (size_t)row * 80;
            ox += pp[h * 8 + p * 2 + 0];
            oy += pp[h * 8 + p * 2 + 1];
            lg += pp[48 + tid];
        }
        float rx = refp[row * 2 + 0], ry = refp[row * 2 + 1];
        float x = (rx + ox * (1.0f / HW_DIM)) * HW_DIM - 0.5f;
        float y = (ry + oy * (1.0f / HW_DIM)) * HW_DIM - 0.5f;
        float fx = floorf(x), fy = floorf(y);
        int x0 = (int)fx, y0 = (int)fy;
        int x1 = x0 + 1, y1 = y0 + 1;
        float wx = x - fx, wy = y - fy;
        float vx0 = (x0 >= 0 && x0 < HW_DIM) ? 1.f : 0.f;
        float vx1 = (x1 >= 0 && x1 < HW_DIM) ? 1.f : 0.f;
        float vy0 = (y0 >= 0 && y0 < HW_DIM) ? 1.f : 0.f;
        float vy1 = (y1 >= 0 && y1 < HW_DIM) ? 1.f : 0.f;
        int xc0 = min(max(x0, 0), HW_DIM - 1), xc1 = min(max(x1, 0), HW_DIM - 1);
        int yc0 = min(max(y0, 0), HW_DIM - 1), yc1 = min(max(y1, 0), HW_DIM - 1);
        int base = b * NV * DIM;
        s_o[0][tid] = base + (yc0 * HW_DIM + xc0) * DIM;
        s_o[1][tid] = base + (yc0 * HW_DIM + xc1) * DIM;
        s_o[2][tid] = base + (yc1 * HW_DIM + xc0) * DIM;
        s_o[3][tid] = base + (yc1 * HW_DIM + xc1) * DIM;
        s_w[0][tid] = (1.f - wy) * (1.f - wx) * vy0 * vx0;
        s_w[1][tid] = (1.f - wy) * wx * vy0 * vx1;
        s_w[2][tid] = wy * (1.f - wx) * vy1 * vx0;
        s_w[3][tid] = wy * wx * vy1 * vx1;
        s_e[tid] = lg;
        float m = s_e[0];
        #pragma unroll
        for (int i = 1; i < 24; i++) m = fmaxf(m, s_e[i]);
        s_e[tid] = expf(lg - m);
    }
    __syncthreads();
    float ssum = 0.0f;
    #pragma unroll
    for (int i = 0; i < 24; i++) ssum += s_e[i];
    float inv = 1.0f / ssum;

    int h = tid >> 6;
    int d2 = (tid & 63) * 2;
    const u16* vb = v + h * HD + d2;
    float a0 = 0.0f, a1 = 0.0f;
    #pragma unroll
    for (int p = 0; p < 4; p++) {
        int idx = h * 4 + p;
        float aw = s_e[idx] * inv;
        #pragma unroll
        for (int c = 0; c < 4; c++) {
            u32 u = *(const u32*)(vb + s_o[c][idx]);
            float w = aw * s_w[c][idx];
            a0 += w * __uint_as_float(u << 16);
            a1 += w * __uint_as_float(u & 0xffff0000u);
        }
    }
    u32 pack = (u32)f2bf(a0) | ((u32)f2bf(a1) << 16);
    *(u32*)&out[(size_t)row * DIM + h * HD + d2] = pack;
}

extern "C" void kernel_launch(void* const* d_in, const int* in_sizes, int n_in,
                              void* d_out, int out_size, void* d_ws, size_t ws_size,
                              hipStream_t stream) {
    const float* query = (const float*)d_in[0];
    const float* refp  = (const float*)d_in[1];
    const float* feat  = (const float*)d_in[2];
    const float* ln_w  = (const float*)d_in[5];
    const float* ln_b  = (const float*)d_in[6];
    const float* vp_w  = (const float*)d_in[7];
    const float* vp_b  = (const float*)d_in[8];
    const float* off_w = (const float*)d_in[9];
    const float* off_b = (const float*)d_in[10];
    const float* aw_w  = (const float*)d_in[11];
    const float* aw_b  = (const float*)d_in[12];
    const float* out_w = (const float*)d_in[13];
    const float* out_b = (const float*)d_in[14];
    const float* gamma = (const float*)d_in[15];

    const size_t MD = (size_t)M_TOTAL * DIM;      // 6291456
    char* ws = (char*)d_ws;
    u16* q_bf    = (u16*)ws;                 ws += MD * 2;
    u16* v_bf    = (u16*)ws;                 ws += MD * 2;
    u16* s_bf    = (u16*)ws;                 ws += MD * 2;
    u16* vp_wt   = (u16*)ws;                 ws += (size_t)DIM * DIM * 2;
    u16* out_wt  = (u16*)ws;                 ws += (size_t)DIM * DIM * 2;
    u16* oaw_wt  = (u16*)ws;                 ws += (size_t)80 * KDIM * 2;
    float* oa    = (float*)ws;               ws += (size_t)KSPLIT * M_TOTAL * 80 * 4;
    float* out_f = (float*)d_out;

    ln_bf_kernel<<<M_TOTAL / 4, 256, 0, stream>>>(query, ln_w, ln_b, q_bf);
    transpose_all<<<dim3(24, 24, 3), 256, 0, stream>>>(vp_w, vp_wt, out_w, out_wt,
                                                       off_w, aw_w, oaw_wt);
    // value = feat @ vp_w + vp_b   (fp32 A staged in-kernel, bf16 out)
    gemm_bt<1><<<GEMM_GRID, 256, 0, stream>>>(feat, vp_wt, vp_b, v_bf,
                                              1, nullptr, nullptr);
    // offsets + aw logits fused, K split 4 ways
    gemm_small<<<dim3(128, KSPLIT), 256, 0, stream>>>(q_bf, oaw_wt, off_b, aw_b, oa, M_TOTAL, KDIM);
    // sampling
    sample_kernel<<<M_TOTAL, 384, 0, stream>>>(oa, refp, v_bf, s_bf);
    // out = query + gamma * (s @ out_w + out_b)
    gemm_bt<0><<<GEMM_GRID, 256, 0, stream>>>(s_bf, out_wt, out_b, out_f,
                                              0, query, gamma);
}

// Round 6
// 180.658 us; speedup vs baseline: 1.1111x; 1.1111x over previous
//
#include <hip/hip_runtime.h>
#include <hip/hip_bf16.h>
#include <math.h>

#define BSZ 2
#define NQ 4096
#define DIM 768
#define HEADS 6
#define POINTS 4
#define HD 128
#define HW_DIM 64
#define NV (HW_DIM*HW_DIM)
#define M_TOTAL (BSZ*NQ)   // 8192
#define KDIM 768
#define KSPLIT 4
#define KPART (KDIM/KSPLIT)  // 192

#define BM 64
#define BN 128
#define BKK 64
#define NBLK_M (M_TOTAL/BM)   // 128
#define NBLK_N (DIM/BN)       // 6
#define GEMM_GRID (NBLK_M*NBLK_N) // 768
#define LN_BLOCKS (M_TOTAL/4)     // 2048
#define TR_BLOCKS (576+576+72)    // 1224

typedef __attribute__((ext_vector_type(8))) short bf16x8;
typedef __attribute__((ext_vector_type(4))) float f32x4;
typedef unsigned int u32;
typedef unsigned short u16;

__device__ inline u16 f2bf(float f) {
    union { float f; u32 u; } v; v.f = f;
    u32 r = v.u + 0x7fffu + ((v.u >> 16) & 1u);
    return (u16)(r >> 16);
}

#define GLD16(g, l) __builtin_amdgcn_global_load_lds( \
    (const __attribute__((address_space(1))) u32*)(g), \
    (__attribute__((address_space(3))) u32*)(l), 16, 0, 0)

// ============ K1: LN(+feat cvt) and weight transposes, union grid ==========
__global__ __launch_bounds__(256) void prep_kernel(
        const float* __restrict__ x, const float* __restrict__ lnw,
        const float* __restrict__ lnb, u16* __restrict__ q,
        const float* __restrict__ feat, u16* __restrict__ feat_bf,
        const float* __restrict__ vp_w,  u16* __restrict__ vp_wt,
        const float* __restrict__ out_w, u16* __restrict__ out_wt,
        const float* __restrict__ off_w, const float* __restrict__ aw_w,
        u16* __restrict__ oaw_wt) {
    int b = blockIdx.x;
    if (b < LN_BLOCKS) {
        // ---- LayerNorm wave-per-row + fused feat fp32->bf16 ----
        int wave = threadIdx.x >> 6, lane = threadIdx.x & 63;
        int row = b * 4 + wave;
        int c = lane * 4;
        const float* xr = x + (size_t)row * DIM;
        const float* fr = feat + (size_t)row * DIM;
        float4 v0 = *(const float4*)(xr + c);
        float4 v1 = *(const float4*)(xr + c + 256);
        float4 v2 = *(const float4*)(xr + c + 512);
        float4 f0 = *(const float4*)(fr + c);
        float4 f1 = *(const float4*)(fr + c + 256);
        float4 f2 = *(const float4*)(fr + c + 512);
        u16* fb = feat_bf + (size_t)row * DIM;
        ushort4 fo;
        fo.x = f2bf(f0.x); fo.y = f2bf(f0.y); fo.z = f2bf(f0.z); fo.w = f2bf(f0.w);
        *(ushort4*)(fb + c) = fo;
        fo.x = f2bf(f1.x); fo.y = f2bf(f1.y); fo.z = f2bf(f1.z); fo.w = f2bf(f1.w);
        *(ushort4*)(fb + c + 256) = fo;
        fo.x = f2bf(f2.x); fo.y = f2bf(f2.y); fo.z = f2bf(f2.z); fo.w = f2bf(f2.w);
        *(ushort4*)(fb + c + 512) = fo;

        float s  = v0.x+v0.y+v0.z+v0.w + v1.x+v1.y+v1.z+v1.w + v2.x+v2.y+v2.z+v2.w;
        float ss = v0.x*v0.x+v0.y*v0.y+v0.z*v0.z+v0.w*v0.w
                 + v1.x*v1.x+v1.y*v1.y+v1.z*v1.z+v1.w*v1.w
                 + v2.x*v2.x+v2.y*v2.y+v2.z*v2.z+v2.w*v2.w;
        #pragma unroll
        for (int st = 1; st < 64; st <<= 1) {
            s  += __shfl_xor(s,  st, 64);
            ss += __shfl_xor(ss, st, 64);
        }
        float mean = s * (1.0f / DIM);
        float var  = ss * (1.0f / DIM) - mean * mean;
        float rstd = rsqrtf(var + 1e-6f);
        u16* qr = q + (size_t)row * DIM;
        #pragma unroll
        for (int g = 0; g < 3; g++) {
            float4 v = (g == 0) ? v0 : (g == 1) ? v1 : v2;
            int cc = c + g * 256;
            const float4 ww = *(const float4*)(lnw + cc);
            const float4 bb = *(const float4*)(lnb + cc);
            ushort4 o;
            o.x = f2bf((v.x - mean) * rstd * ww.x + bb.x);
            o.y = f2bf((v.y - mean) * rstd * ww.y + bb.y);
            o.z = f2bf((v.z - mean) * rstd * ww.z + bb.z);
            o.w = f2bf((v.w - mean) * rstd * ww.w + bb.w);
            *(ushort4*)(qr + cc) = o;
        }
    } else {
        // ---- weight transpose+convert ----
        int t = b - LN_BLOCKS;
        int z, xk, yk;
        if (t < 576)      { z = 0; xk = t % 24; yk = t / 24; }
        else if (t < 1152){ z = 1; t -= 576; xk = t % 24; yk = t / 24; }
        else              { z = 2; t -= 1152; xk = t % 3; yk = t / 3; }
        __shared__ float tile[32][33];
        int n0 = xk * 32, k0 = yk * 32;
        int tx = threadIdx.x & 31, ty = threadIdx.x >> 5;
        const float* src = (z == 0) ? vp_w : (z == 1) ? out_w : nullptr;
        u16* dst = (z == 0) ? vp_wt : (z == 1) ? out_wt : oaw_wt;
        #pragma unroll
        for (int r = 0; r < 4; r++) {
            int k = k0 + ty + r * 8, n = n0 + tx;
            float v = 0.0f;
            if (z < 2) {
                v = src[(size_t)k * DIM + n];
            } else {
                if (n < 48) v = off_w[(size_t)k * 48 + n];
                else if (n < 72) v = aw_w[(size_t)k * 24 + (n - 48)];
            }
            tile[ty + r * 8][tx] = v;
        }
        __syncthreads();
        #pragma unroll
        for (int r = 0; r < 4; r++) {
            int nn = ty + r * 8, kk = tx;
            int drow = n0 + nn;
            if (z == 2 && drow >= 80) continue;
            dst[(size_t)drow * KDIM + k0 + kk] = f2bf(tile[kk][nn]);
        }
    }
}

// ============ big-GEMM body: 64x128 tile, BK=64, XCD-swizzled ==============
__device__ __forceinline__ void gemm_big_body(int b,
        const u16* __restrict__ A, const u16* __restrict__ Bt,
        const float* __restrict__ bias, void* __restrict__ Cout,
        int storeBF16, const float* __restrict__ resid,
        const float* __restrict__ gamma) {
    __shared__ u16 As[BM * BKK];   // 8 KB
    __shared__ u16 Bs[BN * BKK];   // 16 KB
    int tid = threadIdx.x, w = tid >> 6, lane = tid & 63;
    int lm = lane & 15, quad = lane >> 4;
    int xcd = b & 7, idx = b >> 3;        // idx: 0..95
    int mb = xcd * 16 + idx / NBLK_N;
    int nb = idx % NBLK_N;
    int m0 = mb * BM, n0 = nb * BN;
    int wr = w & 1, wc = w >> 1;

    int srow = lane >> 3;               // 0..7
    int scol = (lane & 7) ^ srow;       // XOR-swizzled source col-block
    const u16* Ab = A + (size_t)m0 * KDIM;
    const u16* Bb = Bt + (size_t)n0 * KDIM;

    f32x4 acc[2][4];
    #pragma unroll
    for (int i = 0; i < 2; i++)
        #pragma unroll
        for (int j = 0; j < 4; j++) acc[i][j] = (f32x4){0.f, 0.f, 0.f, 0.f};

    const u16* aaddr[2][2];
    const u16* baddr[4][2];
    #pragma unroll
    for (int i = 0; i < 2; i++) {
        int row = wr * 32 + i * 16 + lm;
        #pragma unroll
        for (int kk = 0; kk < 2; kk++)
            aaddr[i][kk] = &As[row * BKK + (((quad + 4 * kk) ^ (row & 7)) << 3)];
    }
    #pragma unroll
    for (int j = 0; j < 4; j++) {
        int row = wc * 64 + j * 16 + lm;
        #pragma unroll
        for (int kk = 0; kk < 2; kk++)
            baddr[j][kk] = &Bs[row * BKK + (((quad + 4 * kk) ^ (row & 7)) << 3)];
    }

    for (int k0 = 0; k0 < KDIM; k0 += BKK) {
        #pragma unroll
        for (int r = 0; r < 2; r++) {
            int row = r * 32 + w * 8 + srow;
            GLD16(Ab + (size_t)row * KDIM + k0 + scol * 8, &As[(r * 32 + w * 8) * BKK]);
        }
        #pragma unroll
        for (int r = 0; r < 4; r++) {
            int row = r * 32 + w * 8 + srow;
            GLD16(Bb + (size_t)row * KDIM + k0 + scol * 8, &Bs[(r * 32 + w * 8) * BKK]);
        }
        __syncthreads();
        #pragma unroll
        for (int kk = 0; kk < 2; kk++) {
            bf16x8 af[2], bf[4];
            #pragma unroll
            for (int i = 0; i < 2; i++) af[i] = *(const bf16x8*)aaddr[i][kk];
            #pragma unroll
            for (int j = 0; j < 4; j++) bf[j] = *(const bf16x8*)baddr[j][kk];
            #pragma unroll
            for (int i = 0; i < 2; i++)
                #pragma unroll
                for (int j = 0; j < 4; j++)
                    acc[i][j] = __builtin_amdgcn_mfma_f32_16x16x32_bf16(af[i], bf[j], acc[i][j], 0, 0, 0);
        }
        __syncthreads();
    }

    #pragma unroll
    for (int j = 0; j < 4; j++) {
        int col = n0 + wc * 64 + j * 16 + lm;
        float bb = bias[col];
        #pragma unroll
        for (int i = 0; i < 2; i++) {
            #pragma unroll
            for (int r = 0; r < 4; r++) {
                int row = m0 + wr * 32 + i * 16 + quad * 4 + r;
                size_t idxo = (size_t)row * DIM + col;
                float v = acc[i][j][r] + bb;
                if (storeBF16) {
                    ((u16*)Cout)[idxo] = f2bf(v);
                } else {
                    ((float*)Cout)[idxo] = resid[idxo] + gamma[col] * v;
                }
            }
        }
    }
}

// ============ small-GEMM body: q[M][Kpart] * Wt[80][Kpart] ================
__device__ __forceinline__ void gemm_small_body(int mblk, int part,
        const u16* __restrict__ A, const u16* __restrict__ Bt,
        const float* __restrict__ b0, const float* __restrict__ b1,
        float* __restrict__ C) {
    __shared__ u16 As2[64 * 32];
    __shared__ u16 Bs2[80 * 32];
    int tid = threadIdx.x, wave = tid >> 6, lane = tid & 63;
    int lm = lane & 15, quad = lane >> 4;
    int m0 = mblk * 64;
    int kbase = part * KPART;
    f32x4 acc[5];
    #pragma unroll
    for (int i = 0; i < 5; i++) acc[i] = (f32x4){0.f, 0.f, 0.f, 0.f};
    int lrow = lane >> 2, lcol = (lane & 3) * 8;

    for (int k0 = kbase; k0 < kbase + KPART; k0 += 32) {
        for (int c = wave; c < 9; c += 4) {
            if (c < 4) {
                GLD16(A + (size_t)(m0 + c * 16 + lrow) * KDIM + k0 + lcol, &As2[c * 16 * 32]);
            } else {
                GLD16(Bt + (size_t)((c - 4) * 16 + lrow) * KDIM + k0 + lcol, &Bs2[(c - 4) * 16 * 32]);
            }
        }
        __syncthreads();
        bf16x8 af = *(const bf16x8*)&As2[(wave * 16 + lm) * 32 + quad * 8];
        #pragma unroll
        for (int bn = 0; bn < 5; bn++) {
            bf16x8 bv = *(const bf16x8*)&Bs2[(bn * 16 + lm) * 32 + quad * 8];
            acc[bn] = __builtin_amdgcn_mfma_f32_16x16x32_bf16(af, bv, acc[bn], 0, 0, 0);
        }
        __syncthreads();
    }
    float* Cp = C + (size_t)part * M_TOTAL * 80;
    #pragma unroll
    for (int bn = 0; bn < 5; bn++) {
        int col = bn * 16 + lm;
        float bb = 0.0f;
        if (part == 0) bb = (col < 48) ? b0[col] : ((col < 72) ? b1[col - 48] : 0.0f);
        #pragma unroll
        for (int r = 0; r < 4; r++) {
            int row = m0 + wave * 16 + quad * 4 + r;
            Cp[(size_t)row * 80 + col] = acc[bn][r] + bb;
        }
    }
}

// ============ K2: value-GEMM + offsets/aw-GEMM, union grid =================
__global__ __launch_bounds__(256, 3) void gemms_kernel(
        const u16* __restrict__ feat_bf, const u16* __restrict__ vp_wt,
        const float* __restrict__ vp_b, u16* __restrict__ v_bf,
        const u16* __restrict__ q_bf, const u16* __restrict__ oaw_wt,
        const float* __restrict__ off_b, const float* __restrict__ aw_b,
        float* __restrict__ oa) {
    int b = blockIdx.x;
    if (b < GEMM_GRID) {
        gemm_big_body(b, feat_bf, vp_wt, vp_b, v_bf, 1, nullptr, nullptr);
    } else {
        int t = b - GEMM_GRID;
        gemm_small_body(t & 127, t >> 7, q_bf, oaw_wt, off_b, aw_b, oa);
    }
}

// ============ K4: out-GEMM with residual epilogue ==========================
__global__ __launch_bounds__(256, 3) void outgemm_kernel(
        const u16* __restrict__ s_bf, const u16* __restrict__ out_wt,
        const float* __restrict__ out_b, float* __restrict__ out_f,
        const float* __restrict__ query, const float* __restrict__ gamma) {
    gemm_big_body(blockIdx.x, s_bf, out_wt, out_b, out_f, 0, query, gamma);
}

// ============ K3: softmax(24) + bilinear sampling ==========================
__global__ __launch_bounds__(384) void sample_kernel(
        const float* __restrict__ oa, const float* __restrict__ refp,
        const u16* __restrict__ v, u16* __restrict__ out) {
    int row = blockIdx.x;
    int b = row >> 12;                 // NQ = 4096
    int tid = threadIdx.x;
    __shared__ float s_w[4][24];
    __shared__ int   s_o[4][24];
    __shared__ float s_e[24];
    if (tid < 24) {
        int h = tid >> 2, p = tid & 3;
        float ox = 0.f, oy = 0.f, lg = 0.f;
        #pragma unroll
        for (int part = 0; part < KSPLIT; part++) {
            const float* pp = oa + (size_t)part * M_TOTAL * 80 + (size_t)row * 80;
            ox += pp[h * 8 + p * 2 + 0];
            oy += pp[h * 8 + p * 2 + 1];
            lg += pp[48 + tid];
        }
        float rx = refp[row * 2 + 0], ry = refp[row * 2 + 1];
        float x = (rx + ox * (1.0f / HW_DIM)) * HW_DIM - 0.5f;
        float y = (ry + oy * (1.0f / HW_DIM)) * HW_DIM - 0.5f;
        float fx = floorf(x), fy = floorf(y);
        int x0 = (int)fx, y0 = (int)fy;
        int x1 = x0 + 1, y1 = y0 + 1;
        float wx = x - fx, wy = y - fy;
        float vx0 = (x0 >= 0 && x0 < HW_DIM) ? 1.f : 0.f;
        float vx1 = (x1 >= 0 && x1 < HW_DIM) ? 1.f : 0.f;
        float vy0 = (y0 >= 0 && y0 < HW_DIM) ? 1.f : 0.f;
        float vy1 = (y1 >= 0 && y1 < HW_DIM) ? 1.f : 0.f;
        int xc0 = min(max(x0, 0), HW_DIM - 1), xc1 = min(max(x1, 0), HW_DIM - 1);
        int yc0 = min(max(y0, 0), HW_DIM - 1), yc1 = min(max(y1, 0), HW_DIM - 1);
        int base = b * NV * DIM;
        s_o[0][tid] = base + (yc0 * HW_DIM + xc0) * DIM;
        s_o[1][tid] = base + (yc0 * HW_DIM + xc1) * DIM;
        s_o[2][tid] = base + (yc1 * HW_DIM + xc0) * DIM;
        s_o[3][tid] = base + (yc1 * HW_DIM + xc1) * DIM;
        s_w[0][tid] = (1.f - wy) * (1.f - wx) * vy0 * vx0;
        s_w[1][tid] = (1.f - wy) * wx * vy0 * vx1;
        s_w[2][tid] = wy * (1.f - wx) * vy1 * vx0;
        s_w[3][tid] = wy * wx * vy1 * vx1;
        s_e[tid] = lg;
        float m = s_e[0];
        #pragma unroll
        for (int i = 1; i < 24; i++) m = fmaxf(m, s_e[i]);
        s_e[tid] = expf(lg - m);
    }
    __syncthreads();
    float ssum = 0.0f;
    #pragma unroll
    for (int i = 0; i < 24; i++) ssum += s_e[i];
    float inv = 1.0f / ssum;

    int h = tid >> 6;
    int d2 = (tid & 63) * 2;
    const u16* vb = v + h * HD + d2;
    float a0 = 0.0f, a1 = 0.0f;
    #pragma unroll
    for (int p = 0; p < 4; p++) {
        int idx = h * 4 + p;
        float aw = s_e[idx] * inv;
        #pragma unroll
        for (int c = 0; c < 4; c++) {
            u32 u = *(const u32*)(vb + s_o[c][idx]);
            float w = aw * s_w[c][idx];
            a0 += w * __uint_as_float(u << 16);
            a1 += w * __uint_as_float(u & 0xffff0000u);
        }
    }
    u32 pack = (u32)f2bf(a0) | ((u32)f2bf(a1) << 16);
    *(u32*)&out[(size_t)row * DIM + h * HD + d2] = pack;
}

extern "C" void kernel_launch(void* const* d_in, const int* in_sizes, int n_in,
                              void* d_out, int out_size, void* d_ws, size_t ws_size,
                              hipStream_t stream) {
    const float* query = (const float*)d_in[0];
    const float* refp  = (const float*)d_in[1];
    const float* feat  = (const float*)d_in[2];
    const float* ln_w  = (const float*)d_in[5];
    const float* ln_b  = (const float*)d_in[6];
    const float* vp_w  = (const float*)d_in[7];
    const float* vp_b  = (const float*)d_in[8];
    const float* off_w = (const float*)d_in[9];
    const float* off_b = (const float*)d_in[10];
    const float* aw_w  = (const float*)d_in[11];
    const float* aw_b  = (const float*)d_in[12];
    const float* out_w = (const float*)d_in[13];
    const float* out_b = (const float*)d_in[14];
    const float* gamma = (const float*)d_in[15];

    const size_t MD = (size_t)M_TOTAL * DIM;      // 6291456
    char* ws = (char*)d_ws;
    u16* q_bf    = (u16*)ws;                 ws += MD * 2;
    u16* feat_bf = (u16*)ws;                 ws += MD * 2;
    u16* v_bf    = (u16*)ws;                 ws += MD * 2;
    u16* s_bf    = (u16*)ws;                 ws += MD * 2;
    u16* vp_wt   = (u16*)ws;                 ws += (size_t)DIM * DIM * 2;
    u16* out_wt  = (u16*)ws;                 ws += (size_t)DIM * DIM * 2;
    u16* oaw_wt  = (u16*)ws;                 ws += (size_t)80 * KDIM * 2;
    float* oa    = (float*)ws;               ws += (size_t)KSPLIT * M_TOTAL * 80 * 4;
    float* out_f = (float*)d_out;

    // K1: LN+feat cvt (2048 blocks) + weight transposes (1224 blocks)
    prep_kernel<<<LN_BLOCKS + TR_BLOCKS, 256, 0, stream>>>(
        query, ln_w, ln_b, q_bf, feat, feat_bf,
        vp_w, vp_wt, out_w, out_wt, off_w, aw_w, oaw_wt);
    // K2: value-GEMM (768) + offsets/aw-GEMM (512)
    gemms_kernel<<<GEMM_GRID + 128 * KSPLIT, 256, 0, stream>>>(
        feat_bf, vp_wt, vp_b, v_bf, q_bf, oaw_wt, off_b, aw_b, oa);
    // K3: sampling
    sample_kernel<<<M_TOTAL, 384, 0, stream>>>(oa, refp, v_bf, s_bf);
    // K4: out = query + gamma * (s @ out_w + out_b)
    outgemm_kernel<<<GEMM_GRID, 256, 0, stream>>>(s_bf, out_wt, out_b, out_f, query, gamma);
}

// Round 7
// 177.597 us; speedup vs baseline: 1.1302x; 1.0172x over previous
//
#include <hip/hip_runtime.h>
#include <hip/hip_bf16.h>
#include <math.h>

#define BSZ 2
#define NQ 4096
#define DIM 768
#define HEADS 6
#define POINTS 4
#define HD 128
#define HW_DIM 64
#define NV (HW_DIM*HW_DIM)
#define M_TOTAL (BSZ*NQ)   // 8192
#define KDIM 768
#define KSPLIT 2
#define KPART (KDIM/KSPLIT)  // 384

#define BM 64
#define BN 128
#define BKK 64
#define NBLK_M (M_TOTAL/BM)   // 128
#define NBLK_N (DIM/BN)       // 6
#define GEMM_GRID (NBLK_M*NBLK_N) // 768
#define LN_BLOCKS (M_TOTAL/4)     // 2048
#define TR_BLOCKS (576+576+72)    // 1224

typedef __attribute__((ext_vector_type(8))) short bf16x8;
typedef __attribute__((ext_vector_type(4))) float f32x4;
typedef unsigned int u32;
typedef unsigned short u16;

__device__ inline u16 f2bf(float f) {
    union { float f; u32 u; } v; v.f = f;
    u32 r = v.u + 0x7fffu + ((v.u >> 16) & 1u);
    return (u16)(r >> 16);
}

#define GLD16(g, l) __builtin_amdgcn_global_load_lds( \
    (const __attribute__((address_space(1))) u32*)(g), \
    (__attribute__((address_space(3))) u32*)(l), 16, 0, 0)

// ============ K1: LN(+feat cvt) and weight transposes, union grid ==========
__global__ __launch_bounds__(256) void prep_kernel(
        const float* __restrict__ x, const float* __restrict__ lnw,
        const float* __restrict__ lnb, u16* __restrict__ q,
        const float* __restrict__ feat, u16* __restrict__ feat_bf,
        const float* __restrict__ vp_w,  u16* __restrict__ vp_wt,
        const float* __restrict__ out_w, u16* __restrict__ out_wt,
        const float* __restrict__ off_w, const float* __restrict__ aw_w,
        u16* __restrict__ oaw_wt) {
    int b = blockIdx.x;
    if (b < LN_BLOCKS) {
        int wave = threadIdx.x >> 6, lane = threadIdx.x & 63;
        int row = b * 4 + wave;
        int c = lane * 4;
        const float* xr = x + (size_t)row * DIM;
        const float* fr = feat + (size_t)row * DIM;
        float4 v0 = *(const float4*)(xr + c);
        float4 v1 = *(const float4*)(xr + c + 256);
        float4 v2 = *(const float4*)(xr + c + 512);
        float4 f0 = *(const float4*)(fr + c);
        float4 f1 = *(const float4*)(fr + c + 256);
        float4 f2 = *(const float4*)(fr + c + 512);
        u16* fb = feat_bf + (size_t)row * DIM;
        ushort4 fo;
        fo.x = f2bf(f0.x); fo.y = f2bf(f0.y); fo.z = f2bf(f0.z); fo.w = f2bf(f0.w);
        *(ushort4*)(fb + c) = fo;
        fo.x = f2bf(f1.x); fo.y = f2bf(f1.y); fo.z = f2bf(f1.z); fo.w = f2bf(f1.w);
        *(ushort4*)(fb + c + 256) = fo;
        fo.x = f2bf(f2.x); fo.y = f2bf(f2.y); fo.z = f2bf(f2.z); fo.w = f2bf(f2.w);
        *(ushort4*)(fb + c + 512) = fo;

        float s  = v0.x+v0.y+v0.z+v0.w + v1.x+v1.y+v1.z+v1.w + v2.x+v2.y+v2.z+v2.w;
        float ss = v0.x*v0.x+v0.y*v0.y+v0.z*v0.z+v0.w*v0.w
                 + v1.x*v1.x+v1.y*v1.y+v1.z*v1.z+v1.w*v1.w
                 + v2.x*v2.x+v2.y*v2.y+v2.z*v2.z+v2.w*v2.w;
        #pragma unroll
        for (int st = 1; st < 64; st <<= 1) {
            s  += __shfl_xor(s,  st, 64);
            ss += __shfl_xor(ss, st, 64);
        }
        float mean = s * (1.0f / DIM);
        float var  = ss * (1.0f / DIM) - mean * mean;
        float rstd = rsqrtf(var + 1e-6f);
        u16* qr = q + (size_t)row * DIM;
        #pragma unroll
        for (int g = 0; g < 3; g++) {
            float4 v = (g == 0) ? v0 : (g == 1) ? v1 : v2;
            int cc = c + g * 256;
            const float4 ww = *(const float4*)(lnw + cc);
            const float4 bb = *(const float4*)(lnb + cc);
            ushort4 o;
            o.x = f2bf((v.x - mean) * rstd * ww.x + bb.x);
            o.y = f2bf((v.y - mean) * rstd * ww.y + bb.y);
            o.z = f2bf((v.z - mean) * rstd * ww.z + bb.z);
            o.w = f2bf((v.w - mean) * rstd * ww.w + bb.w);
            *(ushort4*)(qr + cc) = o;
        }
    } else {
        int t = b - LN_BLOCKS;
        int z, xk, yk;
        if (t < 576)      { z = 0; xk = t % 24; yk = t / 24; }
        else if (t < 1152){ z = 1; t -= 576; xk = t % 24; yk = t / 24; }
        else              { z = 2; t -= 1152; xk = t % 3; yk = t / 3; }
        __shared__ float tile[32][33];
        int n0 = xk * 32, k0 = yk * 32;
        int tx = threadIdx.x & 31, ty = threadIdx.x >> 5;
        const float* src = (z == 0) ? vp_w : (z == 1) ? out_w : nullptr;
        u16* dst = (z == 0) ? vp_wt : (z == 1) ? out_wt : oaw_wt;
        #pragma unroll
        for (int r = 0; r < 4; r++) {
            int k = k0 + ty + r * 8, n = n0 + tx;
            float v = 0.0f;
            if (z < 2) {
                v = src[(size_t)k * DIM + n];
            } else {
                if (n < 48) v = off_w[(size_t)k * 48 + n];
                else if (n < 72) v = aw_w[(size_t)k * 24 + (n - 48)];
            }
            tile[ty + r * 8][tx] = v;
        }
        __syncthreads();
        #pragma unroll
        for (int r = 0; r < 4; r++) {
            int nn = ty + r * 8, kk = tx;
            int drow = n0 + nn;
            if (z == 2 && drow >= 80) continue;
            dst[(size_t)drow * KDIM + k0 + kk] = f2bf(tile[kk][nn]);
        }
    }
}

// ============ big-GEMM body: 64x128 tile, BK=64, XCD-swizzled ==============
__device__ __forceinline__ void gemm_big_body(int b,
        const u16* __restrict__ A, const u16* __restrict__ Bt,
        const float* __restrict__ bias, void* __restrict__ Cout,
        int storeBF16, const float* __restrict__ resid,
        const float* __restrict__ gamma) {
    __shared__ u16 As[BM * BKK];   // 8 KB
    __shared__ u16 Bs[BN * BKK];   // 16 KB
    int tid = threadIdx.x, w = tid >> 6, lane = tid & 63;
    int lm = lane & 15, quad = lane >> 4;
    int xcd = b & 7, idx = b >> 3;        // idx: 0..95
    int mb = xcd * 16 + idx / NBLK_N;
    int nb = idx % NBLK_N;
    int m0 = mb * BM, n0 = nb * BN;
    int wr = w & 1, wc = w >> 1;

    int srow = lane >> 3;               // 0..7
    int scol = (lane & 7) ^ srow;       // XOR-swizzled source col-block
    const u16* Ab = A + (size_t)m0 * KDIM;
    const u16* Bb = Bt + (size_t)n0 * KDIM;

    f32x4 acc[2][4];
    #pragma unroll
    for (int i = 0; i < 2; i++)
        #pragma unroll
        for (int j = 0; j < 4; j++) acc[i][j] = (f32x4){0.f, 0.f, 0.f, 0.f};

    const u16* aaddr[2][2];
    const u16* baddr[4][2];
    #pragma unroll
    for (int i = 0; i < 2; i++) {
        int row = wr * 32 + i * 16 + lm;
        #pragma unroll
        for (int kk = 0; kk < 2; kk++)
            aaddr[i][kk] = &As[row * BKK + (((quad + 4 * kk) ^ (row & 7)) << 3)];
    }
    #pragma unroll
    for (int j = 0; j < 4; j++) {
        int row = wc * 64 + j * 16 + lm;
        #pragma unroll
        for (int kk = 0; kk < 2; kk++)
            baddr[j][kk] = &Bs[row * BKK + (((quad + 4 * kk) ^ (row & 7)) << 3)];
    }

    for (int k0 = 0; k0 < KDIM; k0 += BKK) {
        #pragma unroll
        for (int r = 0; r < 2; r++) {
            int row = r * 32 + w * 8 + srow;
            GLD16(Ab + (size_t)row * KDIM + k0 + scol * 8, &As[(r * 32 + w * 8) * BKK]);
        }
        #pragma unroll
        for (int r = 0; r < 4; r++) {
            int row = r * 32 + w * 8 + srow;
            GLD16(Bb + (size_t)row * KDIM + k0 + scol * 8, &Bs[(r * 32 + w * 8) * BKK]);
        }
        __syncthreads();
        #pragma unroll
        for (int kk = 0; kk < 2; kk++) {
            bf16x8 af[2], bf[4];
            #pragma unroll
            for (int i = 0; i < 2; i++) af[i] = *(const bf16x8*)aaddr[i][kk];
            #pragma unroll
            for (int j = 0; j < 4; j++) bf[j] = *(const bf16x8*)baddr[j][kk];
            #pragma unroll
            for (int i = 0; i < 2; i++)
                #pragma unroll
                for (int j = 0; j < 4; j++)
                    acc[i][j] = __builtin_amdgcn_mfma_f32_16x16x32_bf16(af[i], bf[j], acc[i][j], 0, 0, 0);
        }
        __syncthreads();
    }

    #pragma unroll
    for (int j = 0; j < 4; j++) {
        int col = n0 + wc * 64 + j * 16 + lm;
        float bb = bias[col];
        #pragma unroll
        for (int i = 0; i < 2; i++) {
            #pragma unroll
            for (int r = 0; r < 4; r++) {
                int row = m0 + wr * 32 + i * 16 + quad * 4 + r;
                size_t idxo = (size_t)row * DIM + col;
                float v = acc[i][j][r] + bb;
                if (storeBF16) {
                    ((u16*)Cout)[idxo] = f2bf(v);
                } else {
                    ((float*)Cout)[idxo] = resid[idxo] + gamma[col] * v;
                }
            }
        }
    }
}

// ============ small-GEMM body: q[M][Kpart] * Wt[80][Kpart] ================
__device__ __forceinline__ void gemm_small_body(int mblk, int part,
        const u16* __restrict__ A, const u16* __restrict__ Bt,
        const float* __restrict__ b0, const float* __restrict__ b1,
        float* __restrict__ C) {
    __shared__ u16 As2[64 * 32];
    __shared__ u16 Bs2[80 * 32];
    int tid = threadIdx.x, wave = tid >> 6, lane = tid & 63;
    int lm = lane & 15, quad = lane >> 4;
    int m0 = mblk * 64;
    int kbase = part * KPART;
    f32x4 acc[5];
    #pragma unroll
    for (int i = 0; i < 5; i++) acc[i] = (f32x4){0.f, 0.f, 0.f, 0.f};
    int lrow = lane >> 2, lcol = (lane & 3) * 8;

    for (int k0 = kbase; k0 < kbase + KPART; k0 += 32) {
        for (int c = wave; c < 9; c += 4) {
            if (c < 4) {
                GLD16(A + (size_t)(m0 + c * 16 + lrow) * KDIM + k0 + lcol, &As2[c * 16 * 32]);
            } else {
                GLD16(Bt + (size_t)((c - 4) * 16 + lrow) * KDIM + k0 + lcol, &Bs2[(c - 4) * 16 * 32]);
            }
        }
        __syncthreads();
        bf16x8 af = *(const bf16x8*)&As2[(wave * 16 + lm) * 32 + quad * 8];
        #pragma unroll
        for (int bn = 0; bn < 5; bn++) {
            bf16x8 bv = *(const bf16x8*)&Bs2[(bn * 16 + lm) * 32 + quad * 8];
            acc[bn] = __builtin_amdgcn_mfma_f32_16x16x32_bf16(af, bv, acc[bn], 0, 0, 0);
        }
        __syncthreads();
    }
    float* Cp = C + (size_t)part * M_TOTAL * 80;
    #pragma unroll
    for (int bn = 0; bn < 5; bn++) {
        int col = bn * 16 + lm;
        float bb = 0.0f;
        if (part == 0) bb = (col < 48) ? b0[col] : ((col < 72) ? b1[col - 48] : 0.0f);
        #pragma unroll
        for (int r = 0; r < 4; r++) {
            int row = m0 + wave * 16 + quad * 4 + r;
            Cp[(size_t)row * 80 + col] = acc[bn][r] + bb;
        }
    }
}

// ============ K2: value-GEMM + offsets/aw-GEMM, union grid =================
__global__ __launch_bounds__(256, 4) void gemms_kernel(
        const u16* __restrict__ feat_bf, const u16* __restrict__ vp_wt,
        const float* __restrict__ vp_b, u16* __restrict__ v_bf,
        const u16* __restrict__ q_bf, const u16* __restrict__ oaw_wt,
        const float* __restrict__ off_b, const float* __restrict__ aw_b,
        float* __restrict__ oa) {
    int b = blockIdx.x;
    if (b < GEMM_GRID) {
        gemm_big_body(b, feat_bf, vp_wt, vp_b, v_bf, 1, nullptr, nullptr);
    } else {
        int t = b - GEMM_GRID;
        gemm_small_body(t & 127, t >> 7, q_bf, oaw_wt, off_b, aw_b, oa);
    }
}

// ============ K4: out-GEMM with residual epilogue ==========================
__global__ __launch_bounds__(256, 4) void outgemm_kernel(
        const u16* __restrict__ s_bf, const u16* __restrict__ out_wt,
        const float* __restrict__ out_b, float* __restrict__ out_f,
        const float* __restrict__ query, const float* __restrict__ gamma) {
    gemm_big_body(blockIdx.x, s_bf, out_wt, out_b, out_f, 0, query, gamma);
}

// ============ K3: softmax(24) + bilinear sampling ==========================
// block 192 = 6 heads x 32 lanes; each thread covers 4 consecutive d's (8 B)
__global__ __launch_bounds__(192) void sample_kernel(
        const float* __restrict__ oa, const float* __restrict__ refp,
        const u16* __restrict__ v, u16* __restrict__ out) {
    int row = blockIdx.x;
    int b = row >> 12;                 // NQ = 4096
    int tid = threadIdx.x;
    __shared__ float s_w[4][24];
    __shared__ int   s_o[4][24];
    __shared__ float s_e[24];
    if (tid < 24) {
        int h = tid >> 2, p = tid & 3;
        float ox = 0.f, oy = 0.f, lg = 0.f;
        #pragma unroll
        for (int part = 0; part < KSPLIT; part++) {
            const float* pp = oa + (size_t)part * M_TOTAL * 80 + (size_t)row * 80;
            ox += pp[h * 8 + p * 2 + 0];
            oy += pp[h * 8 + p * 2 + 1];
            lg += pp[48 + tid];
        }
        float rx = refp[row * 2 + 0], ry = refp[row * 2 + 1];
        float x = (rx + ox * (1.0f / HW_DIM)) * HW_DIM - 0.5f;
        float y = (ry + oy * (1.0f / HW_DIM)) * HW_DIM - 0.5f;
        float fx = floorf(x), fy = floorf(y);
        int x0 = (int)fx, y0 = (int)fy;
        int x1 = x0 + 1, y1 = y0 + 1;
        float wx = x - fx, wy = y - fy;
        float vx0 = (x0 >= 0 && x0 < HW_DIM) ? 1.f : 0.f;
        float vx1 = (x1 >= 0 && x1 < HW_DIM) ? 1.f : 0.f;
        float vy0 = (y0 >= 0 && y0 < HW_DIM) ? 1.f : 0.f;
        float vy1 = (y1 >= 0 && y1 < HW_DIM) ? 1.f : 0.f;
        int xc0 = min(max(x0, 0), HW_DIM - 1), xc1 = min(max(x1, 0), HW_DIM - 1);
        int yc0 = min(max(y0, 0), HW_DIM - 1), yc1 = min(max(y1, 0), HW_DIM - 1);
        int base = b * NV * DIM;
        s_o[0][tid] = base + (yc0 * HW_DIM + xc0) * DIM;
        s_o[1][tid] = base + (yc0 * HW_DIM + xc1) * DIM;
        s_o[2][tid] = base + (yc1 * HW_DIM + xc0) * DIM;
        s_o[3][tid] = base + (yc1 * HW_DIM + xc1) * DIM;
        s_w[0][tid] = (1.f - wy) * (1.f - wx) * vy0 * vx0;
        s_w[1][tid] = (1.f - wy) * wx * vy0 * vx1;
        s_w[2][tid] = wy * (1.f - wx) * vy1 * vx0;
        s_w[3][tid] = wy * wx * vy1 * vx1;
        s_e[tid] = lg;
        float m = s_e[0];
        #pragma unroll
        for (int i = 1; i < 24; i++) m = fmaxf(m, s_e[i]);
        s_e[tid] = expf(lg - m);
    }
    __syncthreads();
    float ssum = 0.0f;
    #pragma unroll
    for (int i = 0; i < 24; i++) ssum += s_e[i];
    float inv = 1.0f / ssum;

    int h = tid >> 5;                  // 0..5
    int d4 = (tid & 31) * 4;           // 0..124
    const u16* vb = v + h * HD + d4;
    float a0 = 0.f, a1 = 0.f, a2 = 0.f, a3 = 0.f;
    #pragma unroll
    for (int p = 0; p < 4; p++) {
        int idx = h * 4 + p;
        float aw = s_e[idx] * inv;
        #pragma unroll
        for (int c = 0; c < 4; c++) {
            uint2 u = *(const uint2*)(vb + s_o[c][idx]);
            float w = aw * s_w[c][idx];
            a0 += w * __uint_as_float(u.x << 16);
            a1 += w * __uint_as_float(u.x & 0xffff0000u);
            a2 += w * __uint_as_float(u.y << 16);
            a3 += w * __uint_as_float(u.y & 0xffff0000u);
        }
    }
    uint2 pack;
    pack.x = (u32)f2bf(a0) | ((u32)f2bf(a1) << 16);
    pack.y = (u32)f2bf(a2) | ((u32)f2bf(a3) << 16);
    *(uint2*)&out[(size_t)row * DIM + h * HD + d4] = pack;
}

extern "C" void kernel_launch(void* const* d_in, const int* in_sizes, int n_in,
                              void* d_out, int out_size, void* d_ws, size_t ws_size,
                              hipStream_t stream) {
    const float* query = (const float*)d_in[0];
    const float* refp  = (const float*)d_in[1];
    const float* feat  = (const float*)d_in[2];
    const float* ln_w  = (const float*)d_in[5];
    const float* ln_b  = (const float*)d_in[6];
    const float* vp_w  = (const float*)d_in[7];
    const float* vp_b  = (const float*)d_in[8];
    const float* off_w = (const float*)d_in[9];
    const float* off_b = (const float*)d_in[10];
    const float* aw_w  = (const float*)d_in[11];
    const float* aw_b  = (const float*)d_in[12];
    const float* out_w = (const float*)d_in[13];
    const float* out_b = (const float*)d_in[14];
    const float* gamma = (const float*)d_in[15];

    const size_t MD = (size_t)M_TOTAL * DIM;      // 6291456
    char* ws = (char*)d_ws;
    u16* q_bf    = (u16*)ws;                 ws += MD * 2;
    u16* feat_bf = (u16*)ws;                 ws += MD * 2;
    u16* v_bf    = (u16*)ws;                 ws += MD * 2;
    u16* s_bf    = (u16*)ws;                 ws += MD * 2;
    u16* vp_wt   = (u16*)ws;                 ws += (size_t)DIM * DIM * 2;
    u16* out_wt  = (u16*)ws;                 ws += (size_t)DIM * DIM * 2;
    u16* oaw_wt  = (u16*)ws;                 ws += (size_t)80 * KDIM * 2;
    float* oa    = (float*)ws;               ws += (size_t)KSPLIT * M_TOTAL * 80 * 4;
    float* out_f = (float*)d_out;

    // K1: LN+feat cvt (2048 blocks) + weight transposes (1224 blocks)
    prep_kernel<<<LN_BLOCKS + TR_BLOCKS, 256, 0, stream>>>(
        query, ln_w, ln_b, q_bf, feat, feat_bf,
        vp_w, vp_wt, out_w, out_wt, off_w, aw_w, oaw_wt);
    // K2: value-GEMM (768) + offsets/aw-GEMM (256)
    gemms_kernel<<<GEMM_GRID + 128 * KSPLIT, 256, 0, stream>>>(
        feat_bf, vp_wt, vp_b, v_bf, q_bf, oaw_wt, off_b, aw_b, oa);
    // K3: sampling
    sample_kernel<<<M_TOTAL, 192, 0, stream>>>(oa, refp, v_bf, s_bf);
    // K4: out = query + gamma * (s @ out_w + out_b)
    outgemm_kernel<<<GEMM_GRID, 256, 0, stream>>>(s_bf, out_wt, out_b, out_f, query, gamma);
}

// Round 9
// 174.717 us; speedup vs baseline: 1.1489x; 1.0165x over previous
//
#include <hip/hip_runtime.h>
#include <hip/hip_bf16.h>
#include <math.h>

#define BSZ 2
#define NQ 4096
#define DIM 768
#define HEADS 6
#define POINTS 4
#define HD 128
#define HW_DIM 64
#define NV (HW_DIM*HW_DIM)
#define M_TOTAL (BSZ*NQ)   // 8192
#define KDIM 768
#define KSPLIT 2
#define KPART (KDIM/KSPLIT)  // 384

#define BM 64
#define BN 128
#define BKK 64
#define NBLK_M (M_TOTAL/BM)   // 128
#define NBLK_N (DIM/BN)       // 6
#define GEMM_GRID (NBLK_M*NBLK_N) // 768
#define LN_BLOCKS (M_TOTAL/4)     // 2048
#define TR_BLOCKS (576+576+72)    // 1224

typedef __attribute__((ext_vector_type(8))) short bf16x8;
typedef __attribute__((ext_vector_type(4))) float f32x4;
typedef unsigned int u32;
typedef unsigned short u16;

__device__ inline u16 f2bf(float f) {
    union { float f; u32 u; } v; v.f = f;
    u32 r = v.u + 0x7fffu + ((v.u >> 16) & 1u);
    return (u16)(r >> 16);
}

#define GLD16(g, l) __builtin_amdgcn_global_load_lds( \
    (const __attribute__((address_space(1))) u32*)(g), \
    (__attribute__((address_space(3))) u32*)(l), 16, 0, 0)

// ============ K1: LN(+feat cvt) and weight transposes, union grid ==========
__global__ __launch_bounds__(256) void prep_kernel(
        const float* __restrict__ x, const float* __restrict__ lnw,
        const float* __restrict__ lnb, u16* __restrict__ q,
        const float* __restrict__ feat, u16* __restrict__ feat_bf,
        const float* __restrict__ vp_w,  u16* __restrict__ vp_wt,
        const float* __restrict__ out_w, u16* __restrict__ out_wt,
        const float* __restrict__ off_w, const float* __restrict__ aw_w,
        u16* __restrict__ oaw_wt) {
    int b = blockIdx.x;
    if (b < LN_BLOCKS) {
        int wave = threadIdx.x >> 6, lane = threadIdx.x & 63;
        int row = b * 4 + wave;
        int c = lane * 4;
        const float* xr = x + (size_t)row * DIM;
        const float* fr = feat + (size_t)row * DIM;
        float4 v0 = *(const float4*)(xr + c);
        float4 v1 = *(const float4*)(xr + c + 256);
        float4 v2 = *(const float4*)(xr + c + 512);
        float4 f0 = *(const float4*)(fr + c);
        float4 f1 = *(const float4*)(fr + c + 256);
        float4 f2 = *(const float4*)(fr + c + 512);
        u16* fb = feat_bf + (size_t)row * DIM;
        ushort4 fo;
        fo.x = f2bf(f0.x); fo.y = f2bf(f0.y); fo.z = f2bf(f0.z); fo.w = f2bf(f0.w);
        *(ushort4*)(fb + c) = fo;
        fo.x = f2bf(f1.x); fo.y = f2bf(f1.y); fo.z = f2bf(f1.z); fo.w = f2bf(f1.w);
        *(ushort4*)(fb + c + 256) = fo;
        fo.x = f2bf(f2.x); fo.y = f2bf(f2.y); fo.z = f2bf(f2.z); fo.w = f2bf(f2.w);
        *(ushort4*)(fb + c + 512) = fo;

        float s  = v0.x+v0.y+v0.z+v0.w + v1.x+v1.y+v1.z+v1.w + v2.x+v2.y+v2.z+v2.w;
        float ss = v0.x*v0.x+v0.y*v0.y+v0.z*v0.z+v0.w*v0.w
                 + v1.x*v1.x+v1.y*v1.y+v1.z*v1.z+v1.w*v1.w
                 + v2.x*v2.x+v2.y*v2.y+v2.z*v2.z+v2.w*v2.w;
        #pragma unroll
        for (int st = 1; st < 64; st <<= 1) {
            s  += __shfl_xor(s,  st, 64);
            ss += __shfl_xor(ss, st, 64);
        }
        float mean = s * (1.0f / DIM);
        float var  = ss * (1.0f / DIM) - mean * mean;
        float rstd = rsqrtf(var + 1e-6f);
        u16* qr = q + (size_t)row * DIM;
        #pragma unroll
        for (int g = 0; g < 3; g++) {
            float4 v = (g == 0) ? v0 : (g == 1) ? v1 : v2;
            int cc = c + g * 256;
            const float4 ww = *(const float4*)(lnw + cc);
            const float4 bb = *(const float4*)(lnb + cc);
            ushort4 o;
            o.x = f2bf((v.x - mean) * rstd * ww.x + bb.x);
            o.y = f2bf((v.y - mean) * rstd * ww.y + bb.y);
            o.z = f2bf((v.z - mean) * rstd * ww.z + bb.z);
            o.w = f2bf((v.w - mean) * rstd * ww.w + bb.w);
            *(ushort4*)(qr + cc) = o;
        }
    } else {
        int t = b - LN_BLOCKS;
        int z, xk, yk;
        if (t < 576)      { z = 0; xk = t % 24; yk = t / 24; }
        else if (t < 1152){ z = 1; t -= 576; xk = t % 24; yk = t / 24; }
        else              { z = 2; t -= 1152; xk = t % 3; yk = t / 3; }
        __shared__ float tile[32][33];
        int n0 = xk * 32, k0 = yk * 32;
        int tx = threadIdx.x & 31, ty = threadIdx.x >> 5;
        const float* src = (z == 0) ? vp_w : (z == 1) ? out_w : nullptr;
        u16* dst = (z == 0) ? vp_wt : (z == 1) ? out_wt : oaw_wt;
        #pragma unroll
        for (int r = 0; r < 4; r++) {
            int k = k0 + ty + r * 8, n = n0 + tx;
            float v = 0.0f;
            if (z < 2) {
                v = src[(size_t)k * DIM + n];
            } else {
                if (n < 48) v = off_w[(size_t)k * 48 + n];
                else if (n < 72) v = aw_w[(size_t)k * 24 + (n - 48)];
            }
            tile[ty + r * 8][tx] = v;
        }
        __syncthreads();
        #pragma unroll
        for (int r = 0; r < 4; r++) {
            int nn = ty + r * 8, kk = tx;
            int drow = n0 + nn;
            if (z == 2 && drow >= 80) continue;
            dst[(size_t)drow * KDIM + k0 + kk] = f2bf(tile[kk][nn]);
        }
    }
}

// ============ big-GEMM body: 64x128 tile, BK=64, XCD-swizzled ==============
__device__ __forceinline__ void gemm_big_body(int b,
        const u16* __restrict__ A, const u16* __restrict__ Bt,
        const float* __restrict__ bias, void* __restrict__ Cout,
        int storeBF16, const float* __restrict__ resid,
        const float* __restrict__ gamma) {
    __shared__ u16 As[BM * BKK];   // 8 KB
    __shared__ u16 Bs[BN * BKK];   // 16 KB
    int tid = threadIdx.x, w = tid >> 6, lane = tid & 63;
    int lm = lane & 15, quad = lane >> 4;
    int xcd = b & 7, idx = b >> 3;        // idx: 0..95
    int mb = xcd * 16 + idx / NBLK_N;
    int nb = idx % NBLK_N;
    int m0 = mb * BM, n0 = nb * BN;
    int wr = w & 1, wc = w >> 1;

    int srow = lane >> 3;               // 0..7
    int scol = (lane & 7) ^ srow;       // XOR-swizzled source col-block
    const u16* Ab = A + (size_t)m0 * KDIM;
    const u16* Bb = Bt + (size_t)n0 * KDIM;

    f32x4 acc[2][4];
    #pragma unroll
    for (int i = 0; i < 2; i++)
        #pragma unroll
        for (int j = 0; j < 4; j++) acc[i][j] = (f32x4){0.f, 0.f, 0.f, 0.f};

    const u16* aaddr[2][2];
    const u16* baddr[4][2];
    #pragma unroll
    for (int i = 0; i < 2; i++) {
        int row = wr * 32 + i * 16 + lm;
        #pragma unroll
        for (int kk = 0; kk < 2; kk++)
            aaddr[i][kk] = &As[row * BKK + (((quad + 4 * kk) ^ (row & 7)) << 3)];
    }
    #pragma unroll
    for (int j = 0; j < 4; j++) {
        int row = wc * 64 + j * 16 + lm;
        #pragma unroll
        for (int kk = 0; kk < 2; kk++)
            baddr[j][kk] = &Bs[row * BKK + (((quad + 4 * kk) ^ (row & 7)) << 3)];
    }

    for (int k0 = 0; k0 < KDIM; k0 += BKK) {
        #pragma unroll
        for (int r = 0; r < 2; r++) {
            int row = r * 32 + w * 8 + srow;
            GLD16(Ab + (size_t)row * KDIM + k0 + scol * 8, &As[(r * 32 + w * 8) * BKK]);
        }
        #pragma unroll
        for (int r = 0; r < 4; r++) {
            int row = r * 32 + w * 8 + srow;
            GLD16(Bb + (size_t)row * KDIM + k0 + scol * 8, &Bs[(r * 32 + w * 8) * BKK]);
        }
        __syncthreads();
        #pragma unroll
        for (int kk = 0; kk < 2; kk++) {
            bf16x8 af[2], bf[4];
            #pragma unroll
            for (int i = 0; i < 2; i++) af[i] = *(const bf16x8*)aaddr[i][kk];
            #pragma unroll
            for (int j = 0; j < 4; j++) bf[j] = *(const bf16x8*)baddr[j][kk];
            #pragma unroll
            for (int i = 0; i < 2; i++)
                #pragma unroll
                for (int j = 0; j < 4; j++)
                    acc[i][j] = __builtin_amdgcn_mfma_f32_16x16x32_bf16(af[i], bf[j], acc[i][j], 0, 0, 0);
        }
        __syncthreads();
    }

    #pragma unroll
    for (int j = 0; j < 4; j++) {
        int col = n0 + wc * 64 + j * 16 + lm;
        float bb = bias[col];
        #pragma unroll
        for (int i = 0; i < 2; i++) {
            #pragma unroll
            for (int r = 0; r < 4; r++) {
                int row = m0 + wr * 32 + i * 16 + quad * 4 + r;
                size_t idxo = (size_t)row * DIM + col;
                float v = acc[i][j][r] + bb;
                if (storeBF16) {
                    ((u16*)Cout)[idxo] = f2bf(v);
                } else {
                    ((float*)Cout)[idxo] = resid[idxo] + gamma[col] * v;
                }
            }
        }
    }
}

// ============ small-GEMM body: q[M][Kpart] * Wt[80][Kpart] ================
__device__ __forceinline__ void gemm_small_body(int mblk, int part,
        const u16* __restrict__ A, const u16* __restrict__ Bt,
        const float* __restrict__ b0, const float* __restrict__ b1,
        float* __restrict__ C) {
    __shared__ u16 As2[64 * 32];
    __shared__ u16 Bs2[80 * 32];
    int tid = threadIdx.x, wave = tid >> 6, lane = tid & 63;
    int lm = lane & 15, quad = lane >> 4;
    int m0 = mblk * 64;
    int kbase = part * KPART;
    f32x4 acc[5];
    #pragma unroll
    for (int i = 0; i < 5; i++) acc[i] = (f32x4){0.f, 0.f, 0.f, 0.f};
    int lrow = lane >> 2, lcol = (lane & 3) * 8;

    for (int k0 = kbase; k0 < kbase + KPART; k0 += 32) {
        for (int c = wave; c < 9; c += 4) {
            if (c < 4) {
                GLD16(A + (size_t)(m0 + c * 16 + lrow) * KDIM + k0 + lcol, &As2[c * 16 * 32]);
            } else {
                GLD16(Bt + (size_t)((c - 4) * 16 + lrow) * KDIM + k0 + lcol, &Bs2[(c - 4) * 16 * 32]);
            }
        }
        __syncthreads();
        bf16x8 af = *(const bf16x8*)&As2[(wave * 16 + lm) * 32 + quad * 8];
        #pragma unroll
        for (int bn = 0; bn < 5; bn++) {
            bf16x8 bv = *(const bf16x8*)&Bs2[(bn * 16 + lm) * 32 + quad * 8];
            acc[bn] = __builtin_amdgcn_mfma_f32_16x16x32_bf16(af, bv, acc[bn], 0, 0, 0);
        }
        __syncthreads();
    }
    float* Cp = C + (size_t)part * M_TOTAL * 80;
    #pragma unroll
    for (int bn = 0; bn < 5; bn++) {
        int col = bn * 16 + lm;
        float bb = 0.0f;
        if (part == 0) bb = (col < 48) ? b0[col] : ((col < 72) ? b1[col - 48] : 0.0f);
        #pragma unroll
        for (int r = 0; r < 4; r++) {
            int row = m0 + wave * 16 + quad * 4 + r;
            Cp[(size_t)row * 80 + col] = acc[bn][r] + bb;
        }
    }
}

// ============ K2: value-GEMM + offsets/aw-GEMM, union grid =================
__global__ __launch_bounds__(256, 4) void gemms_kernel(
        const u16* __restrict__ feat_bf, const u16* __restrict__ vp_wt,
        const float* __restrict__ vp_b, u16* __restrict__ v_bf,
        const u16* __restrict__ q_bf, const u16* __restrict__ oaw_wt,
        const float* __restrict__ off_b, const float* __restrict__ aw_b,
        float* __restrict__ oa) {
    int b = blockIdx.x;
    if (b < GEMM_GRID) {
        gemm_big_body(b, feat_bf, vp_wt, vp_b, v_bf, 1, nullptr, nullptr);
    } else {
        int t = b - GEMM_GRID;
        gemm_small_body(t & 127, t >> 7, q_bf, oaw_wt, off_b, aw_b, oa);
    }
}

// ============ K4: out-GEMM with residual epilogue ==========================
__global__ __launch_bounds__(256, 4) void outgemm_kernel(
        const u16* __restrict__ s_bf, const u16* __restrict__ out_wt,
        const float* __restrict__ out_b, float* __restrict__ out_f,
        const float* __restrict__ query, const float* __restrict__ gamma) {
    gemm_big_body(blockIdx.x, s_bf, out_wt, out_b, out_f, 0, query, gamma);
}

// ============ K3: softmax(24) + bilinear sampling ==========================
// block 192 = 6 heads x 32 lanes; each thread covers 4 consecutive d's (8 B)
__global__ __launch_bounds__(192) void sample_kernel(
        const float* __restrict__ oa, const float* __restrict__ refp,
        const u16* __restrict__ v, u16* __restrict__ out) {
    int row = blockIdx.x;
    int b = row >> 12;                 // NQ = 4096
    int tid = threadIdx.x;
    __shared__ float s_w[4][24];
    __shared__ int   s_o[4][24];
    __shared__ float s_e[24];
    if (tid < 24) {
        int h = tid >> 2, p = tid & 3;
        float ox = 0.f, oy = 0.f, lg = 0.f;
        #pragma unroll
        for (int part = 0; part < KSPLIT; part++) {
            const float* pp = oa + (size_t)part * M_TOTAL * 80 + (size_t)row * 80;
            ox += pp[h * 8 + p * 2 + 0];
            oy += pp[h * 8 + p * 2 + 1];
            lg += pp[48 + tid];
        }
        float rx = refp[row * 2 + 0], ry = refp[row * 2 + 1];
        float x = (rx + ox * (1.0f / HW_DIM)) * HW_DIM - 0.5f;
        float y = (ry + oy * (1.0f / HW_DIM)) * HW_DIM - 0.5f;
        float fx = floorf(x), fy = floorf(y);
        int x0 = (int)fx, y0 = (int)fy;
        int x1 = x0 + 1, y1 = y0 + 1;
        float wx = x - fx, wy = y - fy;
        float vx0 = (x0 >= 0 && x0 < HW_DIM) ? 1.f : 0.f;
        float vx1 = (x1 >= 0 && x1 < HW_DIM) ? 1.f : 0.f;
        float vy0 = (y0 >= 0 && y0 < HW_DIM) ? 1.f : 0.f;
        float vy1 = (y1 >= 0 && y1 < HW_DIM) ? 1.f : 0.f;
        int xc0 = min(max(x0, 0), HW_DIM - 1), xc1 = min(max(x1, 0), HW_DIM - 1);
        int yc0 = min(max(y0, 0), HW_DIM - 1), yc1 = min(max(y1, 0), HW_DIM - 1);
        int base = b * NV * DIM;
        s_o[0][tid] = base + (yc0 * HW_DIM + xc0) * DIM;
        s_o[1][tid] = base + (yc0 * HW_DIM + xc1) * DIM;
        s_o[2][tid] = base + (yc1 * HW_DIM + xc0) * DIM;
        s_o[3][tid] = base + (yc1 * HW_DIM + xc1) * DIM;
        s_w[0][tid] = (1.f - wy) * (1.f - wx) * vy0 * vx0;
        s_w[1][tid] = (1.f - wy) * wx * vy0 * vx1;
        s_w[2][tid] = wy * (1.f - wx) * vy1 * vx0;
        s_w[3][tid] = wy * wx * vy1 * vx1;
        s_e[tid] = lg;
        float m = s_e[0];
        #pragma unroll
        for (int i = 1; i < 24; i++) m = fmaxf(m, s_e[i]);
        s_e[tid] = expf(lg - m);
    }
    __syncthreads();
    float ssum = 0.0f;
    #pragma unroll
    for (int i = 0; i < 24; i++) ssum += s_e[i];
    float inv = 1.0f / ssum;

    int h = tid >> 5;                  // 0..5
    int d4 = (tid & 31) * 4;           // 0..124
    const u16* vb = v + h * HD + d4;
    float a0 = 0.f, a1 = 0.f, a2 = 0.f, a3 = 0.f;
    #pragma unroll
    for (int p = 0; p < 4; p++) {
        int idx = h * 4 + p;
        float aw = s_e[idx] * inv;
        #pragma unroll
        for (int c = 0; c < 4; c++) {
            uint2 u = *(const uint2*)(vb + s_o[c][idx]);
            float w = aw * s_w[c][idx];
            a0 += w * __uint_as_float(u.x << 16);
            a1 += w * __uint_as_float(u.x & 0xffff0000u);
            a2 += w * __uint_as_float(u.y << 16);
            a3 += w * __uint_as_float(u.y & 0xffff0000u);
        }
    }
    uint2 pack;
    pack.x = (u32)f2bf(a0) | ((u32)f2bf(a1) << 16);
    pack.y = (u32)f2bf(a2) | ((u32)f2bf(a3) << 16);
    *(uint2*)&out[(size_t)row * DIM + h * HD + d4] = pack;
}

extern "C" void kernel_launch(void* const* d_in, const int* in_sizes, int n_in,
                              void* d_out, int out_size, void* d_ws, size_t ws_size,
                              hipStream_t stream) {
    const float* query = (const float*)d_in[0];
    const float* refp  = (const float*)d_in[1];
    const float* feat  = (const float*)d_in[2];
    const float* ln_w  = (const float*)d_in[5];
    const float* ln_b  = (const float*)d_in[6];
    const float* vp_w  = (const float*)d_in[7];
    const float* vp_b  = (const float*)d_in[8];
    const float* off_w = (const float*)d_in[9];
    const float* off_b = (const float*)d_in[10];
    const float* aw_w  = (const float*)d_in[11];
    const float* aw_b  = (const float*)d_in[12];
    const float* out_w = (const float*)d_in[13];
    const float* out_b = (const float*)d_in[14];
    const float* gamma = (const float*)d_in[15];

    const size_t MD = (size_t)M_TOTAL * DIM;      // 6291456
    char* ws = (char*)d_ws;
    u16* q_bf    = (u16*)ws;                 ws += MD * 2;
    u16* feat_bf = (u16*)ws;                 ws += MD * 2;
    u16* v_bf    = (u16*)ws;                 ws += MD * 2;
    u16* s_bf    = (u16*)ws;                 ws += MD * 2;
    u16* vp_wt   = (u16*)ws;                 ws += (size_t)DIM * DIM * 2;
    u16* out_wt  = (u16*)ws;                 ws += (size_t)DIM * DIM * 2;
    u16* oaw_wt  = (u16*)ws;                 ws += (size_t)80 * KDIM * 2;
    float* oa    = (float*)ws;               ws += (size_t)KSPLIT * M_TOTAL * 80 * 4;
    float* out_f = (float*)d_out;

    // K1: LN+feat cvt (2048 blocks) + weight transposes (1224 blocks)
    prep_kernel<<<LN_BLOCKS + TR_BLOCKS, 256, 0, stream>>>(
        query, ln_w, ln_b, q_bf, feat, feat_bf,
        vp_w, vp_wt, out_w, out_wt, off_w, aw_w, oaw_wt);
    // K2: value-GEMM (768) + offsets/aw-GEMM (256)
    gemms_kernel<<<GEMM_GRID + 128 * KSPLIT, 256, 0, stream>>>(
        feat_bf, vp_wt, vp_b, v_bf, q_bf, oaw_wt, off_b, aw_b, oa);
    // K3: sampling
    sample_kernel<<<M_TOTAL, 192, 0, stream>>>(oa, refp, v_bf, s_bf);
    // K4: out = query + gamma * (s @ out_w + out_b)
    outgemm_kernel<<<GEMM_GRID, 256, 0, stream>>>(s_bf, out_wt, out_b, out_f, query, gamma);
}